// Round 14
// baseline (325.506 us; speedup 1.0000x reference)
//
#include <hip/hip_runtime.h>
#include <hip/hip_bf16.h>
#include <math.h>

// Problem dims (fixed by reference)
#define BATCH   2
#define SEQ     2048
#define D_MODEL 1024
#define NHEAD   16
#define HEADD   64
#define NROWS   (BATCH * SEQ)   // 4096
#define D_FF    4096
#define TPARTS  4               // attention t-split factor
#define TSPAN   (SEQ / TPARTS)  // 512

typedef __bf16 bf16_t;
typedef __bf16 bf16x2 __attribute__((ext_vector_type(2)));
typedef __bf16 bf16x4 __attribute__((ext_vector_type(4)));
typedef __bf16 bf16x8 __attribute__((ext_vector_type(8)));
typedef float  f32x4  __attribute__((ext_vector_type(4)));

#define QSCALE 0.18033688011112042f   // 0.125 * log2(e), folded into Q

// async global->LDS, 16B per lane, dest = wave-uniform base + lane*16
__device__ __forceinline__ void gload_lds16(const void* g, void* l) {
    __builtin_amdgcn_global_load_lds(
        (const __attribute__((address_space(1))) unsigned int*)g,
        (__attribute__((address_space(3))) unsigned int*)l, 16, 0, 0);
}

// ---------------------------------------------------------------------------
// Fused weight transpose + fp32 -> bf16 for all six weights (one launch).
// ---------------------------------------------------------------------------
__global__ __launch_bounds__(256) void transpose_all6(
    const float* __restrict__ Wq, const float* __restrict__ Wk,
    const float* __restrict__ Wv, const float* __restrict__ Wp,
    const float* __restrict__ W1, const float* __restrict__ W2,
    bf16_t* __restrict__ Wqkvt, bf16_t* __restrict__ Wpt,
    bf16_t* __restrict__ W1t, bf16_t* __restrict__ W2t)
{
    __shared__ float tile[32][33];
    int bid = blockIdx.x;
    const float* W; bf16_t* Wt; int K, N, n0, k0;
    if (bid < 4096) {
        int seg = bid >> 10, t = bid & 1023;
        W  = (seg == 0) ? Wq : (seg == 1) ? Wk : (seg == 2) ? Wv : Wp;
        Wt = (seg < 3) ? (Wqkvt + (size_t)seg * 1024 * 1024) : Wpt;
        K = 1024; N = 1024;
        n0 = (t & 31) * 32; k0 = (t >> 5) * 32;
    } else if (bid < 8192) {
        int t = bid - 4096;
        W = W1; Wt = W1t; K = 1024; N = 4096;
        n0 = (t & 127) * 32; k0 = (t >> 7) * 32;
    } else {
        int t = bid - 8192;
        W = W2; Wt = W2t; K = 4096; N = 1024;
        n0 = (t & 31) * 32; k0 = (t >> 5) * 32;
    }
    int tx = threadIdx.x;   // 0..31
    int ty = threadIdx.y;   // 0..7
    #pragma unroll
    for (int i = 0; i < 32; i += 8)
        tile[ty + i][tx] = W[(size_t)(k0 + ty + i) * N + n0 + tx];
    __syncthreads();
    #pragma unroll
    for (int i = 0; i < 32; i += 8)
        Wt[(size_t)(n0 + ty + i) * K + k0 + tx] = (bf16_t)tile[tx][ty + i];
}

// ---------------------------------------------------------------------------
// LayerNorm: fp32 [rows][1024] -> bf16 [rows][1024].  One block per row.
// ---------------------------------------------------------------------------
__global__ __launch_bounds__(256) void ln_kernel(
    const float* __restrict__ x, const float* __restrict__ g,
    const float* __restrict__ b, bf16_t* __restrict__ out)
{
    int row = blockIdx.x;
    int tid = threadIdx.x;
    const float* xr = x + (size_t)row * D_MODEL;
    f32x4 v = *(const f32x4*)(xr + tid * 4);
    float s  = v[0] + v[1] + v[2] + v[3];
    float s2 = v[0]*v[0] + v[1]*v[1] + v[2]*v[2] + v[3]*v[3];
    #pragma unroll
    for (int off = 32; off; off >>= 1) {
        s  += __shfl_down(s, off);
        s2 += __shfl_down(s2, off);
    }
    __shared__ float ps[4], ps2[4];
    int w = tid >> 6, lane = tid & 63;
    if (lane == 0) { ps[w] = s; ps2[w] = s2; }
    __syncthreads();
    float sum  = ps[0] + ps[1] + ps[2] + ps[3];
    float sum2 = ps2[0] + ps2[1] + ps2[2] + ps2[3];
    float mu  = sum * (1.0f / D_MODEL);
    float var = sum2 * (1.0f / D_MODEL) - mu * mu;
    float rs  = rsqrtf(var + 1e-5f);
    #pragma unroll
    for (int j = 0; j < 4; ++j) {
        int c = tid * 4 + j;
        out[(size_t)row * D_MODEL + c] = (bf16_t)((v[j] - mu) * rs * g[c] + b[c]);
    }
}

// ---------------------------------------------------------------------------
// 256x256 GEMM, 8-wave, MINIMAL-SYNC loop (R9/R10-proven).
// One vmcnt(0)+s_barrier per K-tile; zero intra-tile barriers; stages into
// buf^1 issued after the top barrier.  Chunk-XOR swizzle (rule #21).
// EPI 2: + bias -> GELU -> bf16.   EPI 6: fused QKV scatter.
// ---------------------------------------------------------------------------
template<int EPI>
__global__ __launch_bounds__(512) void gemm256(
    const bf16_t* __restrict__ A, const bf16_t* __restrict__ Bt,
    const float* __restrict__ bias, void* __restrict__ out,
    int M, int N, int K)
{
    __shared__ bf16_t As[2][256 * 64];   // [buf][row][k]
    __shared__ bf16_t Bs[2][256 * 64];
    int tid = threadIdx.x;               // 0..511
    int bid = blockIdx.x;
    int m0 = (bid & 15) * 256;           // GX = M/256 = 16
    int n0 = (bid >> 4) * 256;
    int w = tid >> 6, lane = tid & 63, quad = lane >> 4, l15 = lane & 15;
    int wm = (w >> 2) * 128;             // 0 or 128
    int wn = (w & 3) * 64;               // 0,64,128,192
    int rxs = l15 & 7;

    // staging: 512 threads, srow 0..63, chunk (tid&7); covers 64 rows/round
    int srow = tid >> 3;
    int sxor = (((tid & 7) ^ (srow & 7)) << 3);
    const bf16_t* Ap = A  + (size_t)(m0 + srow) * K + sxor;
    const bf16_t* Bp = Bt + (size_t)(n0 + srow) * K + sxor;

    f32x4 acc[8][4] = {};

    int nt = K >> 6;
    // prologue: K-tile 0 -> buf 0 (A+B, 2 halves x 2 rounds each)
    {
        bf16_t* AsW = &As[0][w * 512];
        bf16_t* BsW = &Bs[0][w * 512];
        #pragma unroll
        for (int h = 0; h < 2; ++h)
            #pragma unroll
            for (int p = 0; p < 2; ++p) {
                gload_lds16(Ap + (size_t)(h * 128 + p * 64) * K, AsW + h * 8192 + p * 4096);
                gload_lds16(Bp + (size_t)(h * 128 + p * 64) * K, BsW + h * 8192 + p * 4096);
            }
    }

    for (int t = 0; t < nt; ++t) {
        int cur = t & 1;
        const bf16_t* Asc = &As[cur][0];
        const bf16_t* Bsc = &Bs[cur][0];
        bf16_t* AsN = &As[cur ^ 1][w * 512];
        bf16_t* BsN = &Bs[cur ^ 1][w * 512];
        bool pf = (t + 1 < nt);
        int k1 = (t + 1) << 6;
        asm volatile("s_waitcnt vmcnt(0)" ::: "memory");
        __builtin_amdgcn_s_barrier();
        __builtin_amdgcn_sched_barrier(0);

        bf16x8 bfr[4][2];
        #pragma unroll
        for (int q = 0; q < 4; ++q) {
            bf16x8 af[2][2];
            #pragma unroll
            for (int ii = 0; ii < 2; ++ii)
                #pragma unroll
                for (int kk = 0; kk < 2; ++kk)
                    af[ii][kk] = *(const bf16x8*)&Asc[(wm + (2 * q + ii) * 16 + l15) * 64
                                                      + (((kk * 4 + quad) ^ rxs) << 3)];
            if (q == 0) {
                #pragma unroll
                for (int j = 0; j < 4; ++j)
                    #pragma unroll
                    for (int kk = 0; kk < 2; ++kk)
                        bfr[j][kk] = *(const bf16x8*)&Bsc[(wn + j * 16 + l15) * 64
                                                          + (((kk * 4 + quad) ^ rxs) << 3)];
            }
            if (q == 0 && pf) {
                #pragma unroll
                for (int h = 0; h < 2; ++h)
                    #pragma unroll
                    for (int p = 0; p < 2; ++p)
                        gload_lds16(Ap + (size_t)(h * 128 + p * 64) * K + k1,
                                    AsN + h * 8192 + p * 4096);
            }
            if (q == 1 && pf) {
                #pragma unroll
                for (int h = 0; h < 2; ++h)
                    #pragma unroll
                    for (int p = 0; p < 2; ++p)
                        gload_lds16(Bp + (size_t)(h * 128 + p * 64) * K + k1,
                                    BsN + h * 8192 + p * 4096);
            }
            #pragma unroll
            for (int ii = 0; ii < 2; ++ii)
                #pragma unroll
                for (int j = 0; j < 4; ++j)
                    #pragma unroll
                    for (int kk = 0; kk < 2; ++kk)
                        acc[2 * q + ii][j] = __builtin_amdgcn_mfma_f32_16x16x32_bf16(
                            af[ii][kk], bfr[j][kk], acc[2 * q + ii][j], 0, 0, 0);
        }
    }

    #pragma unroll
    for (int i = 0; i < 8; ++i)
    #pragma unroll
    for (int j = 0; j < 4; ++j) {
        int col  = n0 + wn + j * 16 + l15;
        int row0 = m0 + wm + i * 16 + quad * 4;
        if (EPI == 6) {
            int region = (n0 + wn + j * 16) >> 10;   // 0=Q 1=K 2=V (uniform per j-tile)
            if (region < 2) {
                #pragma unroll
                for (int r = 0; r < 4; ++r) {
                    int row = row0 + r;
                    float v = acc[i][j][r];
                    if (region == 0) v *= QSCALE;
                    int b = row >> 11, s = row & 2047, hh = (col & 1023) >> 6, d = col & 63;
                    bf16_t* dst = (bf16_t*)out + (size_t)region * 4194304;
                    dst[(((size_t)(b * NHEAD + hh)) * SEQ + s) * HEADD + d] = (bf16_t)v;
                }
            } else {
                int dg = col - 2048, hh = dg >> 6, d = dg & 63;
                int b = row0 >> 11, s0 = row0 & 2047;
                bf16x4 pv;
                #pragma unroll
                for (int r = 0; r < 4; ++r) pv[r] = (bf16_t)acc[i][j][r];
                *(bf16x4*)((bf16_t*)out + 8388608
                           + (((size_t)(b * NHEAD + hh)) * HEADD + d) * SEQ + s0) = pv;
            }
        } else {
            float bv = bias[col];
            #pragma unroll
            for (int r = 0; r < 4; ++r) {
                int row = row0 + r;
                float u = acc[i][j][r] + bv;
                float y = u * (0.7978845608028654f + 0.03567740814f * u * u);
                float e = __builtin_amdgcn_exp2f(2.8853900817779268f * y);
                float r8 = __builtin_amdgcn_rcpf(e + 1.0f);
                ((bf16_t*)out)[(size_t)row * N + col] = (bf16_t)(u - u * r8);
            }
        }
    }
}

// ---------------------------------------------------------------------------
// 128x128xBK=128 GEMM, 8-wave, minimal-sync loop (R20/R21/R23):
// R13 counters: khalf-split killed the 6.29M conflicts (now 0) -- but
// MfmaUtil 24% / HBM 18% with zero conflicts = exposed HBM latency at
// 1 blk/CU: tile t+1's loads were issued at half0/half1 (~150-300cy cover
// vs ~900cy HBM latency for the streamed act).  R23: issue ALL 8 stages
// immediately after the top barrier -> full-tile (~600cy) cover.  Legal by
// the R9 argument: buf^1's prior readers finished before this barrier
// (their ds_reads fed MFMAs that issued before the barrier in program
// order).  LDS budget forbids a 3rd buffer (192KB > 160KB).
// Layout (R21-proven): two k-half sub-tiles, each bit-identical to the
// proven BK=64 geometry (128B rows, 3-bit slot XOR, conflicts 0).
// grid = 32x8 = 256 blocks = full CU coverage at N=1024.
// EPI 1: + bias + bf16 residual -> fp32.  EPI 3: + bias + fp32 resid -> fp32.
// ---------------------------------------------------------------------------
template<int EPI>
__global__ __launch_bounds__(512) void gemm128sq(
    const bf16_t* __restrict__ A, const bf16_t* __restrict__ Bt,
    const float* __restrict__ bias, const void* __restrict__ resid,
    void* __restrict__ out, int M, int N, int K)
{
    __shared__ bf16_t As[2][2][128 * 64];   // [buf][khalf][row*64]
    __shared__ bf16_t Bs[2][2][128 * 64];
    int tid = threadIdx.x;                // 0..511
    int bid = blockIdx.x;
    int m0 = (bid & 31) * 128;            // GX = 32
    int n0 = (bid >> 5) * 128;
    int w = tid >> 6, lane = tid & 63, quad = lane >> 4, l15 = lane & 15;
    int wm = (w >> 2) * 64;               // 0 or 64
    int wn = (w & 3) * 32;                // 0,32,64,96
    int rxs = l15 & 7;

    // staging: 4 rounds/operand; round p: khalf = p>>1, rows (p&1)*64+srow
    int srow = tid >> 3;                  // 0..63
    int sxor = (((tid & 7) ^ (srow & 7)) << 3);
    const bf16_t* Ap = A  + (size_t)(m0 + srow) * K + sxor;
    const bf16_t* Bp = Bt + (size_t)(n0 + srow) * K + sxor;

    f32x4 acc[4][2] = {};
    int nt = K >> 7;

    // prologue: tile 0 -> buf 0 (A rounds 0-3, B rounds 0-3)
    {
        #pragma unroll
        for (int p = 0; p < 4; ++p) {
            gload_lds16(Ap + (size_t)((p & 1) * 64) * K + (p >> 1) * 64,
                        &As[0][p >> 1][(p & 1) * 4096 + w * 512]);
            gload_lds16(Bp + (size_t)((p & 1) * 64) * K + (p >> 1) * 64,
                        &Bs[0][p >> 1][(p & 1) * 4096 + w * 512]);
        }
    }

    for (int t = 0; t < nt; ++t) {
        int cur = t & 1;
        bool pf = (t + 1 < nt);
        int k1 = (t + 1) << 7;
        // K-tile top: tile t landed (issued a full tile ago); publish; buf^1's
        // prior readers finished before this barrier (reads feed MFMAs).
        asm volatile("s_waitcnt vmcnt(0)" ::: "memory");
        __builtin_amdgcn_s_barrier();
        __builtin_amdgcn_sched_barrier(0);
        // R23: issue next tile's ALL stages here -> full-tile latency cover.
        if (pf) {
            #pragma unroll
            for (int p = 0; p < 4; ++p) {
                gload_lds16(Ap + (size_t)((p & 1) * 64) * K + k1 + (p >> 1) * 64,
                            &As[cur ^ 1][p >> 1][(p & 1) * 4096 + w * 512]);
                gload_lds16(Bp + (size_t)((p & 1) * 64) * K + k1 + (p >> 1) * 64,
                            &Bs[cur ^ 1][p >> 1][(p & 1) * 4096 + w * 512]);
            }
        }

        bf16x8 bfr[2][4];
        #pragma unroll
        for (int half = 0; half < 2; ++half) {
            bf16x8 af[2][4];
            #pragma unroll
            for (int ii = 0; ii < 2; ++ii)
                #pragma unroll
                for (int kk = 0; kk < 4; ++kk)
                    af[ii][kk] = *(const bf16x8*)&As[cur][kk >> 1]
                        [(wm + (2 * half + ii) * 16 + l15) * 64
                         + ((((kk & 1) * 4 + quad) ^ rxs) << 3)];
            if (half == 0) {
                #pragma unroll
                for (int j = 0; j < 2; ++j)
                    #pragma unroll
                    for (int kk = 0; kk < 4; ++kk)
                        bfr[j][kk] = *(const bf16x8*)&Bs[cur][kk >> 1]
                            [(wn + j * 16 + l15) * 64
                             + ((((kk & 1) * 4 + quad) ^ rxs) << 3)];
            }
            #pragma unroll
            for (int ii = 0; ii < 2; ++ii)
                #pragma unroll
                for (int j = 0; j < 2; ++j)
                    #pragma unroll
                    for (int kk = 0; kk < 4; ++kk)
                        acc[2 * half + ii][j] = __builtin_amdgcn_mfma_f32_16x16x32_bf16(
                            af[ii][kk], bfr[j][kk], acc[2 * half + ii][j], 0, 0, 0);
        }
    }

    #pragma unroll
    for (int i = 0; i < 4; ++i)
    #pragma unroll
    for (int j = 0; j < 2; ++j) {
        int col  = n0 + wn + j * 16 + l15;
        int row0 = m0 + wm + i * 16 + quad * 4;
        float bv = bias[col];
        #pragma unroll
        for (int r = 0; r < 4; ++r) {
            int row = row0 + r;
            float vacc = acc[i][j][r] + bv;
            if (EPI == 1) {
                float res = (float)((const bf16_t*)resid)[(size_t)row * N + col];
                ((float*)out)[(size_t)row * N + col] = vacc + res;
            } else {
                float res = ((const float*)resid)[(size_t)row * N + col];
                ((float*)out)[(size_t)row * N + col] = vacc + res;
            }
        }
    }
}

// ---------------------------------------------------------------------------
// Attention partial kernel.  No-max softmax (Q pre-scaled; exp2 direct) is
// LINEAR in t -> TPARTS=4 t-ranges of 512; partial o (bf16) + partial l.
// R23: the 72-pad Ks layout measured 4,194,304 bank conflicts = EXACTLY
// 32 extra cyc/wave-iter = the 4 kb reads at 2x cost (quarter-wave phase
// model: dword-stride 36 -> only 4 distinct bank-spans per 16-lane phase).
// Fix: Ks -> [32][64] (128B rows, 16B-aligned) with slot-XOR keyed on
// (row>>1)&7 (row&7 fails: kb rows are even).  Reg-staged -> swizzle
// applied identically at ds_write and read; bijective per row.
// ---------------------------------------------------------------------------
__global__ __launch_bounds__(256, 4) void attn_kernel(
    const bf16_t* __restrict__ q, const bf16_t* __restrict__ k,
    const bf16_t* __restrict__ vt, bf16_t* __restrict__ po,
    float* __restrict__ plsum)
{
    int gid = blockIdx.x;                 // 0..2047
    int xcd = gid & 7;                    // presumed XCD (any bijection safe)
    int loc = gid >> 3;                   // 0..255
    int bh  = xcd * 4 + (loc >> 6);       // 4 consecutive heads per XCD
    int rest = loc & 63;
    int qt   = rest >> 2;                 // q-tile 0..15
    int part = rest & 3;                  // t-part 0..3
    int tb0 = part * TSPAN, tend = tb0 + TSPAN;
    int b = bh >> 4, h = bh & 15;
    int tid = threadIdx.x, w = tid >> 6, lane = tid & 63;
    int quad = lane >> 4, l15 = lane & 15;
    int qbase = qt * 128 + w * 32;
    const bf16_t* qh = q  + (size_t)bh * SEQ * HEADD;
    const bf16_t* kh = k  + (size_t)bh * SEQ * HEADD;
    const bf16_t* vh = vt + (size_t)bh * HEADD * SEQ;   // [d][t]

    bf16x8 qa[2][2];
    #pragma unroll
    for (int m = 0; m < 2; ++m)
        #pragma unroll
        for (int hf = 0; hf < 2; ++hf)
            qa[m][hf] = *(const bf16x8*)(qh + (size_t)(qbase + m * 16 + l15) * HEADD + hf * 32 + quad * 8);

    bf16x8 ones;
    #pragma unroll
    for (int j = 0; j < 8; ++j) ones[j] = (bf16_t)1.0f;

    __shared__ alignas(16) bf16_t Ks[32 * 64];     // [t][slot-swz], 128B rows
    __shared__ alignas(16) bf16_t Vs[64 * 40];     // [d][t], rows padded to 40
    __shared__ alignas(16) bf16_t Pl[4][32][40];   // per-wave P (32q x 32t)

    // staging indices: K tile is rows of 64; V tile is 64 rows x 64B
    int ksrow = tid >> 3, kschunk = tid & 7;       // t-row, d-chunk idx
    int vsrow = tid >> 2, vscol = (tid & 3) * 8;   // d-row, t-chunk
    const bf16_t* kg = kh + (size_t)ksrow * HEADD + kschunk * 8;
    const bf16_t* vg = vh + (size_t)vsrow * SEQ + vscol;
    int kslot = (kschunk ^ ((ksrow >> 1) & 7)) << 3;   // swizzled write slot

    f32x4 o[2][4] = {};
    f32x4 ls[2] = {};

    for (int t0 = tb0; t0 < tend; t0 += 32) {
        bf16x8 kreg = *(const bf16x8*)(kg + (size_t)t0 * HEADD);
        bf16x8 vreg = *(const bf16x8*)(vg + t0);
        __syncthreads();                           // prev-iter readers done
        *(bf16x8*)&Ks[ksrow * 64 + kslot] = kreg;
        *(bf16x8*)&Vs[vsrow * 40 + vscol] = vreg;
        __syncthreads();                           // tiles visible

        bf16x8 kb[2][2], vf[4];
        #pragma unroll
        for (int jt = 0; jt < 2; ++jt)
            #pragma unroll
            for (int hf = 0; hf < 2; ++hf)
                kb[jt][hf] = *(const bf16x8*)&Ks[(2 * l15 + jt) * 64
                    + ((((hf << 2) | quad) ^ (l15 & 7)) << 3)];
        #pragma unroll
        for (int dn = 0; dn < 4; ++dn)
            vf[dn] = *(const bf16x8*)&Vs[(dn * 16 + l15) * 40 + quad * 8];

        #pragma unroll
        for (int m = 0; m < 2; ++m) {
            f32x4 sc[2];
            #pragma unroll
            for (int jt = 0; jt < 2; ++jt) {
                f32x4 z = {};
                z = __builtin_amdgcn_mfma_f32_16x16x32_bf16(qa[m][0], kb[jt][0], z, 0, 0, 0);
                z = __builtin_amdgcn_mfma_f32_16x16x32_bf16(qa[m][1], kb[jt][1], z, 0, 0, 0);
                sc[jt] = z;
            }
            int qm = qbase + m * 16;
            bool dg = (t0 < qm + 16) && (t0 + 32 > qm);  // wave-uniform
            #pragma unroll
            for (int r = 0; r < 4; ++r) {
                int qrow = qm + quad * 4 + r;
                float p0 = __builtin_amdgcn_exp2f(sc[0][r]);
                float p1 = __builtin_amdgcn_exp2f(sc[1][r]);
                if (dg) {
                    int tg = t0 + 2 * l15;
                    if (tg == qrow)     p0 = 0.0f;
                    if (tg + 1 == qrow) p1 = 0.0f;
                }
                bf16x2 pp = { (bf16_t)p0, (bf16_t)p1 };
                *(bf16x2*)&Pl[w][m * 16 + quad * 4 + r][2 * l15] = pp;
            }
        }
        #pragma unroll
        for (int m = 0; m < 2; ++m) {
            bf16x8 pf = *(const bf16x8*)&Pl[w][m * 16 + l15][quad * 8];
            ls[m] = __builtin_amdgcn_mfma_f32_16x16x32_bf16(pf, ones, ls[m], 0, 0, 0);
            #pragma unroll
            for (int dn = 0; dn < 4; ++dn)
                o[m][dn] = __builtin_amdgcn_mfma_f32_16x16x32_bf16(pf, vf[dn], o[m][dn], 0, 0, 0);
        }
    }

    // partial o (bf16, undivided) and partial l (fp32; every lane holds full sum)
    #pragma unroll
    for (int m = 0; m < 2; ++m)
        #pragma unroll
        for (int dn = 0; dn < 4; ++dn)
            #pragma unroll
            for (int r = 0; r < 4; ++r) {
                int qrow = qbase + m * 16 + quad * 4 + r;
                po[(((size_t)part * NROWS) + b * SEQ + qrow) * D_MODEL
                   + h * HEADD + dn * 16 + l15] = (bf16_t)o[m][dn][r];
            }
    if (l15 == 0) {
        #pragma unroll
        for (int m = 0; m < 2; ++m)
            #pragma unroll
            for (int r = 0; r < 4; ++r) {
                int qrow = qbase + m * 16 + quad * 4 + r;
                plsum[((size_t)part * 32 + bh) * SEQ + qrow] = ls[m][r];
            }
    }
}

// ---------------------------------------------------------------------------
// Merge attention partials: y = (sum_p o_p) / (sum_p l_p), bf16 out.
// ---------------------------------------------------------------------------
__global__ __launch_bounds__(256) void attn_merge(
    const bf16_t* __restrict__ po, const float* __restrict__ plsum,
    bf16_t* __restrict__ y)
{
    int row = blockIdx.x;
    int tid = threadIdx.x;
    int c = tid * 4;
    int b = row >> 11, s = row & 2047;
    int bh = b * NHEAD + (c >> 6);
    float l = 0.0f;
    f32x4 ov = {};
    #pragma unroll
    for (int p = 0; p < TPARTS; ++p) {
        l += plsum[((size_t)p * 32 + bh) * SEQ + s];
        bf16x4 t = *(const bf16x4*)&po[((size_t)p * NROWS + row) * D_MODEL + c];
        #pragma unroll
        for (int j = 0; j < 4; ++j) ov[j] += (float)t[j];
    }
    float rl = 1.0f / l;
    bf16x4 out;
    #pragma unroll
    for (int j = 0; j < 4; ++j) out[j] = (bf16_t)(ov[j] * rl);
    *(bf16x4*)&y[(size_t)row * D_MODEL + c] = out;
}

// ---------------------------------------------------------------------------
extern "C" void kernel_launch(void* const* d_in, const int* in_sizes, int n_in,
                              void* d_out, int out_size, void* d_ws, size_t ws_size,
                              hipStream_t stream)
{
    const float* x   = (const float*)d_in[0];
    const float* Wk  = (const float*)d_in[1];
    const float* Wq  = (const float*)d_in[2];
    const float* Wv  = (const float*)d_in[3];
    const float* Wp  = (const float*)d_in[4];
    const float* bp  = (const float*)d_in[5];
    const float* g1  = (const float*)d_in[6];
    const float* b1  = (const float*)d_in[7];
    const float* g2  = (const float*)d_in[8];
    const float* b2  = (const float*)d_in[9];
    const float* W1  = (const float*)d_in[10];
    const float* bm1 = (const float*)d_in[11];
    const float* W2  = (const float*)d_in[12];
    const float* bm2 = (const float*)d_in[13];

    char* ws = (char*)d_ws;
    const size_t MB = 1024 * 1024;
    bf16_t* Wqkvt = (bf16_t*)(ws + 0 * MB);  // 6MB [3072][1024]: Q^T|K^T|V^T
    bf16_t* Wpt = (bf16_t*)(ws + 6 * MB);    // 2MB
    bf16_t* W1t = (bf16_t*)(ws + 8 * MB);    // 8MB  [4096][1024]
    bf16_t* W2t = (bf16_t*)(ws + 16 * MB);   // 8MB  [1024][4096]
    bf16_t* xn  = (bf16_t*)(ws + 24 * MB);   // 8MB (live until proj residual)
    bf16_t* qkv = (bf16_t*)(ws + 32 * MB);   // fused QKV out base (24MB)
    bf16_t* qb  = (bf16_t*)(ws + 32 * MB);   // 8MB [b][h][s][d], Q pre-scaled
    bf16_t* kb  = (bf16_t*)(ws + 40 * MB);   // 8MB [b][h][s][d]
    bf16_t* vtb = (bf16_t*)(ws + 48 * MB);   // 8MB [b][h][d][s]
    bf16_t* yb  = (bf16_t*)(ws + 56 * MB);   // 8MB merged attn out
    float*  hbuf= (float*) (ws + 64 * MB);   // 16MB fp32 (written after merge)
    bf16_t* po  = (bf16_t*)(ws + 64 * MB);   // 32MB attn partials (dead at proj)
    float*  pls = (float*) (ws + 96 * MB);   // 1MB  lsum partials
    bf16_t* hn  = (bf16_t*)(ws + 24 * MB);   // reuse xn slot (xn dead by then)
    bf16_t* act = (bf16_t*)(ws + 32 * MB);   // 32MB, reuses qkv region

    transpose_all6<<<12288, dim3(32, 8), 0, stream>>>(
        Wq, Wk, Wv, Wp, W1, W2, Wqkvt, Wpt, W1t, W2t);

    ln_kernel<<<NROWS, 256, 0, stream>>>(x, g1, b1, xn);

    // fused QKV projection: N=3072 -> 256^2 minimal-sync kernel (grid 16x12)
    gemm256<6><<<192, 512, 0, stream>>>(xn, Wqkvt, nullptr, qkv, NROWS, 3072, D_MODEL);

    attn_kernel<<<2048, 256, 0, stream>>>(qb, kb, vtb, po, pls);
    attn_merge<<<NROWS, 256, 0, stream>>>(po, pls, yb);

    // Wp proj: N=1024 -> 128^2 BK=128 8-wave kernel (grid 32x8=256, 1/CU)
    gemm128sq<1><<<256, 512, 0, stream>>>(yb, Wpt, bp, xn, hbuf, NROWS, D_MODEL, D_MODEL);

    ln_kernel<<<NROWS, 256, 0, stream>>>(hbuf, g2, b2, hn);

    // MLP up: N=4096 -> 256^2 minimal-sync kernel (grid 16x16=256)
    gemm256<2><<<256, 512, 0, stream>>>(hn, W1t, bm1, act, NROWS, D_FF, D_MODEL);
    // MLP down: N=1024, K=4096 -> 128^2 BK=128 8-wave kernel (grid 256, 1/CU)
    gemm128sq<3><<<256, 512, 0, stream>>>(act, W2t, bm2, hbuf, d_out, NROWS, D_MODEL, D_FF);
}